// Round 8
// baseline (367.640 us; speedup 1.0000x reference)
//
#include <hip/hip_runtime.h>

#define N_NODES 1048576
#define THR 16.0f

typedef int int4v __attribute__((ext_vector_type(4)));
typedef float float4v __attribute__((ext_vector_type(4)));

// cells of width 16: |dx| < 16 is impossible when |cellx_s - cellx_d| >= 2,
// because cx in cell c means cx in [16c, 16c+16), so celldiff k>=2 implies
// |dx| > 16(k-1) >= 16. Prefilter is exactly conservative (no false rejects)
// since cells are computed from the SAME stored cxy the exact path gathers.
//
// 4 nodes/thread, fully vectorized: float4 in (pos x, pos y, nsx, nsy),
// 2x float4 out (interleaved cxy), ushort4 cell codes, float4 NT zeros.
__global__ void centers_kernel(const float* __restrict__ pos,
                               const float* __restrict__ nsx,
                               const float* __restrict__ nsy,
                               float* __restrict__ cxy,      // [2N] interleaved {cx,cy}
                               unsigned short* __restrict__ cell,
                               float* __restrict__ ex, float* __restrict__ ey,
                               float* __restrict__ out) {
    int t = blockIdx.x * blockDim.x + threadIdx.x;
    int base = t * 4;
    if (base < N_NODES) {
        float4 px = *reinterpret_cast<const float4*>(pos + base);
        float4 py = *reinterpret_cast<const float4*>(pos + N_NODES + base);
        float4 sx = *reinterpret_cast<const float4*>(nsx + base);
        float4 sy = *reinterpret_cast<const float4*>(nsy + base);
        float cx0 = px.x + 0.5f * sx.x, cy0 = py.x + 0.5f * sy.x;
        float cx1 = px.y + 0.5f * sx.y, cy1 = py.y + 0.5f * sy.y;
        float cx2 = px.z + 0.5f * sx.z, cy2 = py.z + 0.5f * sy.z;
        float cx3 = px.w + 0.5f * sx.w, cy3 = py.w + 0.5f * sy.w;
        // interleaved centers: one 8B gather per endpoint on the exact path
        float4 c01 = {cx0, cy0, cx1, cy1};
        float4 c23 = {cx2, cy2, cx3, cy3};
        *reinterpret_cast<float4*>(cxy + 2 * base)     = c01;
        *reinterpret_cast<float4*>(cxy + 2 * base + 4) = c23;
        // x,y >= 0 and < ~1026 -> cells 0..64, fits u8 each. *0.0625f exact (pow2).
        ushort4 cc;
        cc.x = (unsigned short)(((int)(cx0 * 0.0625f)) | (((int)(cy0 * 0.0625f)) << 8));
        cc.y = (unsigned short)(((int)(cx1 * 0.0625f)) | (((int)(cy1 * 0.0625f)) << 8));
        cc.z = (unsigned short)(((int)(cx2 * 0.0625f)) | (((int)(cy2 * 0.0625f)) << 8));
        cc.w = (unsigned short)(((int)(cx3 * 0.0625f)) | (((int)(cy3 * 0.0625f)) << 8));
        *reinterpret_cast<ushort4*>(cell + base) = cc;
        // zero accumulators; NT: these lines are next touched by memory-side atomics
        float4v z = {0.f, 0.f, 0.f, 0.f};
        __builtin_nontemporal_store(z, reinterpret_cast<float4v*>(ex + base));
        __builtin_nontemporal_store(z, reinterpret_cast<float4v*>(ey + base));
    }
    if (t == 0) out[0] = 0.f;   // d_out poisoned by harness; re-init every call
}

__global__ void pairs_kernel(const int* __restrict__ src,
                             const int* __restrict__ dst,
                             const unsigned short* __restrict__ cell,
                             const float* __restrict__ cxy,   // interleaved {cx,cy}
                             float* __restrict__ ex, float* __restrict__ ey,
                             int E) {
    int t = blockIdx.x * blockDim.x + threadIdx.x;
    int base = t * 4;
    if (base >= E) return;
    // streaming index loads: non-temporal so they don't evict the 2MB cell table from L2
    int4v s4 = __builtin_nontemporal_load(reinterpret_cast<const int4v*>(src + base));
    int4v d4 = __builtin_nontemporal_load(reinterpret_cast<const int4v*>(dst + base));
    int ss[4] = {s4.x, s4.y, s4.z, s4.w};
    int dd[4] = {d4.x, d4.y, d4.z, d4.w};
    // issue all 8 cell gathers first (ILP), then evaluate.
    // NT (no-allocate) on the gathers: ~98% L1-miss (2MB table vs 32KB L1), so
    // allocating the 64B fill line into L1 is pure overhead on the TCP fill path
    // (~33.5M fills/call). NT keeps the miss but drops the fill.
    int cs[4], cd[4];
#pragma unroll
    for (int k = 0; k < 4; ++k) {
        cs[k] = __builtin_nontemporal_load(cell + ss[k]);
        cd[k] = __builtin_nontemporal_load(cell + dd[k]);
    }
    const float2* c2 = reinterpret_cast<const float2*>(cxy);
#pragma unroll
    for (int k = 0; k < 4; ++k) {
        int dxc = (cs[k] & 0xff) - (cd[k] & 0xff);
        int dyc = (cs[k] >> 8) - (cd[k] >> 8);
        // pass iff celldiff in {-1,0,1} for both dims (~0.2% of pairs)
        if ((unsigned)(dxc + 1) <= 2u && (unsigned)(dyc + 1) <= 2u) {
            int s = ss[k], d = dd[k];
            float2 ps = c2[s];
            float2 pd = c2[d];
            float dx = ps.x - pd.x;
            float dy = ps.y - pd.y;
            if (fabsf(dx) < THR && fabsf(dy) < THR) {
                float inv = 0.5f / (dx * dx + dy * dy + 0.01f);
                float fx = dx * inv;
                float fy = dy * inv;
                atomicAdd(&ex[s],  fx);
                atomicAdd(&ex[d], -fx);
                atomicAdd(&ey[s],  fy);
                atomicAdd(&ey[d], -fy);
            }
        }
    }
}

__global__ void reduce_kernel(const float* __restrict__ v,  // ex then ey, contiguous 2N
                              float* __restrict__ out, int n4) {
    int t = blockIdx.x * blockDim.x + threadIdx.x;
    int stride = gridDim.x * blockDim.x;
    float sum = 0.f;
    for (int i = t; i < n4; i += stride) {
        float4 a = reinterpret_cast<const float4*>(v)[i];
        sum += fabsf(a.x) + fabsf(a.y) + fabsf(a.z) + fabsf(a.w);
    }
#pragma unroll
    for (int off = 32; off > 0; off >>= 1)
        sum += __shfl_down(sum, off, 64);
    __shared__ float ss[4];
    int wid = threadIdx.x >> 6;
    if ((threadIdx.x & 63) == 0) ss[wid] = sum;
    __syncthreads();
    if (threadIdx.x == 0)
        atomicAdd(out, ss[0] + ss[1] + ss[2] + ss[3]);
}

extern "C" void kernel_launch(void* const* d_in, const int* in_sizes, int n_in,
                              void* d_out, int out_size, void* d_ws, size_t ws_size,
                              hipStream_t stream) {
    const float* pos = (const float*)d_in[0];
    const float* nsx = (const float*)d_in[1];
    const float* nsy = (const float*)d_in[2];
    const int*   src = (const int*)d_in[3];
    const int*   dst = (const int*)d_in[4];
    float* out = (float*)d_out;
    const int E = in_sizes[3];

    float* cxy = (float*)d_ws;                      // [2N] f32 interleaved {cx,cy}
    float* ex  = cxy + 2 * N_NODES;                 // [N]
    float* ey  = ex + N_NODES;                      // [N]  (ex,ey contiguous for reduce)
    unsigned short* cell = (unsigned short*)(ey + N_NODES);  // [N] u16 = 2MB

    // 4 nodes per thread
    centers_kernel<<<N_NODES / (256 * 4), 256, 0, stream>>>(
        pos, nsx, nsy, cxy, cell, ex, ey, out);

    int nt = E / 4;   // E = 16777216
    pairs_kernel<<<(nt + 255) / 256, 256, 0, stream>>>(
        src, dst, cell, cxy, ex, ey, E);

    int n4 = (2 * N_NODES) / 4;
    reduce_kernel<<<2048, 256, 0, stream>>>(ex, out, n4);
}

// Round 9
// 186.626 us; speedup vs baseline: 1.9699x; 1.9699x over previous
//
#include <hip/hip_runtime.h>

#define N_NODES 1048576
#define THR 16.0f

typedef int int4v __attribute__((ext_vector_type(4)));
typedef float float4v __attribute__((ext_vector_type(4)));

// cells of width 16: |dx| < 16 is impossible when |cellx_s - cellx_d| >= 2,
// because cx in cell c means cx in [16c, 16c+16), so celldiff k>=2 implies
// |dx| > 16(k-1) >= 16. Prefilter is exactly conservative (no false rejects)
// since cells are computed from the SAME stored cxy the exact path gathers.
//
// 4 nodes/thread, fully vectorized: float4 in (pos x, pos y, nsx, nsy),
// 2x float4 out (interleaved cxy), ushort4 cell codes, float4 NT zeros.
__global__ void centers_kernel(const float* __restrict__ pos,
                               const float* __restrict__ nsx,
                               const float* __restrict__ nsy,
                               float* __restrict__ cxy,      // [2N] interleaved {cx,cy}
                               unsigned short* __restrict__ cell,
                               float* __restrict__ ex, float* __restrict__ ey,
                               float* __restrict__ out) {
    int t = blockIdx.x * blockDim.x + threadIdx.x;
    int base = t * 4;
    if (base < N_NODES) {
        float4 px = *reinterpret_cast<const float4*>(pos + base);
        float4 py = *reinterpret_cast<const float4*>(pos + N_NODES + base);
        float4 sx = *reinterpret_cast<const float4*>(nsx + base);
        float4 sy = *reinterpret_cast<const float4*>(nsy + base);
        float cx0 = px.x + 0.5f * sx.x, cy0 = py.x + 0.5f * sy.x;
        float cx1 = px.y + 0.5f * sx.y, cy1 = py.y + 0.5f * sy.y;
        float cx2 = px.z + 0.5f * sx.z, cy2 = py.z + 0.5f * sy.z;
        float cx3 = px.w + 0.5f * sx.w, cy3 = py.w + 0.5f * sy.w;
        // interleaved centers: one 8B gather per endpoint on the exact path
        float4 c01 = {cx0, cy0, cx1, cy1};
        float4 c23 = {cx2, cy2, cx3, cy3};
        *reinterpret_cast<float4*>(cxy + 2 * base)     = c01;
        *reinterpret_cast<float4*>(cxy + 2 * base + 4) = c23;
        // x,y >= 0 and < ~1026 -> cells 0..64, fits u8 each. *0.0625f is exact (pow2).
        ushort4 cc;
        cc.x = (unsigned short)(((int)(cx0 * 0.0625f)) | (((int)(cy0 * 0.0625f)) << 8));
        cc.y = (unsigned short)(((int)(cx1 * 0.0625f)) | (((int)(cy1 * 0.0625f)) << 8));
        cc.z = (unsigned short)(((int)(cx2 * 0.0625f)) | (((int)(cy2 * 0.0625f)) << 8));
        cc.w = (unsigned short)(((int)(cx3 * 0.0625f)) | (((int)(cy3 * 0.0625f)) << 8));
        *reinterpret_cast<ushort4*>(cell + base) = cc;
        // zero accumulators; NT: these lines are next touched by memory-side atomics
        float4v z = {0.f, 0.f, 0.f, 0.f};
        __builtin_nontemporal_store(z, reinterpret_cast<float4v*>(ex + base));
        __builtin_nontemporal_store(z, reinterpret_cast<float4v*>(ey + base));
    }
    if (t == 0) out[0] = 0.f;   // d_out poisoned by harness; re-init every call
}

__global__ void pairs_kernel(const int* __restrict__ src,
                             const int* __restrict__ dst,
                             const unsigned short* __restrict__ cell,
                             const float* __restrict__ cxy,   // interleaved {cx,cy}
                             float* __restrict__ ex, float* __restrict__ ey,
                             int E) {
    int t = blockIdx.x * blockDim.x + threadIdx.x;
    int base = t * 4;
    if (base >= E) return;
    // streaming index loads: non-temporal so they don't evict the 2MB cell table from L2.
    // NOTE (round 8): do NOT mark the cell gathers themselves NT — on gfx950 nt
    // no-allocates at L2 too, pushing the table to IF (pairs 155 -> 231 us).
    int4v s4 = __builtin_nontemporal_load(reinterpret_cast<const int4v*>(src + base));
    int4v d4 = __builtin_nontemporal_load(reinterpret_cast<const int4v*>(dst + base));
    int ss[4] = {s4.x, s4.y, s4.z, s4.w};
    int dd[4] = {d4.x, d4.y, d4.z, d4.w};
    // issue all 8 cell gathers first (ILP), then evaluate
    int cs[4], cd[4];
#pragma unroll
    for (int k = 0; k < 4; ++k) { cs[k] = cell[ss[k]]; cd[k] = cell[dd[k]]; }
    const float2* c2 = reinterpret_cast<const float2*>(cxy);
#pragma unroll
    for (int k = 0; k < 4; ++k) {
        int dxc = (cs[k] & 0xff) - (cd[k] & 0xff);
        int dyc = (cs[k] >> 8) - (cd[k] >> 8);
        // pass iff celldiff in {-1,0,1} for both dims (~0.2% of pairs)
        if ((unsigned)(dxc + 1) <= 2u && (unsigned)(dyc + 1) <= 2u) {
            int s = ss[k], d = dd[k];
            float2 ps = c2[s];
            float2 pd = c2[d];
            float dx = ps.x - pd.x;
            float dy = ps.y - pd.y;
            if (fabsf(dx) < THR && fabsf(dy) < THR) {
                float inv = 0.5f / (dx * dx + dy * dy + 0.01f);
                float fx = dx * inv;
                float fy = dy * inv;
                atomicAdd(&ex[s],  fx);
                atomicAdd(&ex[d], -fx);
                atomicAdd(&ey[s],  fy);
                atomicAdd(&ey[d], -fy);
            }
        }
    }
}

__global__ void reduce_kernel(const float* __restrict__ v,  // ex then ey, contiguous 2N
                              float* __restrict__ out, int n4) {
    int t = blockIdx.x * blockDim.x + threadIdx.x;
    int stride = gridDim.x * blockDim.x;
    float sum = 0.f;
    for (int i = t; i < n4; i += stride) {
        float4 a = reinterpret_cast<const float4*>(v)[i];
        sum += fabsf(a.x) + fabsf(a.y) + fabsf(a.z) + fabsf(a.w);
    }
#pragma unroll
    for (int off = 32; off > 0; off >>= 1)
        sum += __shfl_down(sum, off, 64);
    __shared__ float ss[4];
    int wid = threadIdx.x >> 6;
    if ((threadIdx.x & 63) == 0) ss[wid] = sum;
    __syncthreads();
    if (threadIdx.x == 0)
        atomicAdd(out, ss[0] + ss[1] + ss[2] + ss[3]);
}

extern "C" void kernel_launch(void* const* d_in, const int* in_sizes, int n_in,
                              void* d_out, int out_size, void* d_ws, size_t ws_size,
                              hipStream_t stream) {
    const float* pos = (const float*)d_in[0];
    const float* nsx = (const float*)d_in[1];
    const float* nsy = (const float*)d_in[2];
    const int*   src = (const int*)d_in[3];
    const int*   dst = (const int*)d_in[4];
    float* out = (float*)d_out;
    const int E = in_sizes[3];

    float* cxy = (float*)d_ws;                      // [2N] f32 interleaved {cx,cy}
    float* ex  = cxy + 2 * N_NODES;                 // [N]
    float* ey  = ex + N_NODES;                      // [N]  (ex,ey contiguous for reduce)
    unsigned short* cell = (unsigned short*)(ey + N_NODES);  // [N] u16 = 2MB

    // 4 nodes per thread
    centers_kernel<<<N_NODES / (256 * 4), 256, 0, stream>>>(
        pos, nsx, nsy, cxy, cell, ex, ey, out);

    int nt = E / 4;   // E = 16777216
    pairs_kernel<<<(nt + 255) / 256, 256, 0, stream>>>(
        src, dst, cell, cxy, ex, ey, E);

    int n4 = (2 * N_NODES) / 4;
    reduce_kernel<<<2048, 256, 0, stream>>>(ex, out, n4);
}